// Round 1
// 441.651 us; speedup vs baseline: 1.0036x; 1.0036x over previous
//
#include <hip/hip_runtime.h>
#include <math.h>

#define NSL   1048576u   // N slots
#define WW    64         // word width
#define NBLK  4096       // k_main grid (NSL/256)
#define CAP   131072     // global candidate buffer capacity
#define SORTN 2048       // LDS bitonic sort capacity
#define NBINS 2048       // histogram bins for large-M select (bits>>19 of u<0.005 => <0x775)
#define UTH   0.005f     // usage candidate threshold; alloc tail beyond candidates
                         // is <= prod(s_i) < UTH^M -> far below 2e-2 harness threshold

// ws float layout:
// [1]                inv softmax sum (k_select -> k_norm)
// [2]                candidate count (uint, atomic; zeroed by memset node)
// [4 .. 4+NBLK)      per-block exp partial sums (no atomics)
// [8192 .. +CAP)     candidate usage values
// [8192+CAP .. +CAP) candidate slot indices (uint)
#define WS_PART 4
#define WS_CVAL 8192
#define WS_CIDX (8192 + CAP)

// ------------------------------------------------- K1: main streaming pass
// Coalesced layout: each wave handles 64 consecutive rows. Iteration j loads
// 1 KB contiguous (rows R0+4j..R0+4j+3, 16 lanes per row), butterfly-reduces
// dot and |row|^2 within 16-lane groups, then redistributes so lane L holds
// the results for row R0+L.
__global__ __launch_bounds__(256) void k_main(
    const float* __restrict__ mem, const float* __restrict__ key,
    const float* __restrict__ beta, const float* __restrict__ fg,
    const float* __restrict__ rw,  const float* __restrict__ pu,
    const float* __restrict__ wwt,
    float* __restrict__ out, float* __restrict__ ws)
{
    __shared__ float kbuf[WW];
    __shared__ float c_sh;
    __shared__ float part[4];
    int tid = threadIdx.x;
    if (tid < WW / 4) ((float4*)kbuf)[tid] = ((const float4*)key)[tid];
    __syncthreads();
    if (tid < 64) {                       // wave 0: key norm + scale factor
        float x = kbuf[tid];
        float s = x * x;
        #pragma unroll
        for (int off = 32; off > 0; off >>= 1) s += __shfl_down(s, off);
        if (tid == 0) c_sh = beta[0] / fmaxf(sqrtf(s), 1e-8f);
    }
    __syncthreads();

    int w = tid >> 6;                     // wave id 0..3
    int L = tid & 63;                     // lane id
    unsigned int R0 = blockIdx.x * 256u + (unsigned int)(w * 64);  // wave row base
    float4 kf = ((const float4*)kbuf)[L & 15];   // key cols (L%16)*4 .. +4

    const float4* mbase = (const float4*)mem + (size_t)R0 * (WW / 4);

    float myDot = 0.f, myNr = 0.f;        // final values for row R0 + L
    #pragma unroll
    for (int j = 0; j < 16; ++j) {
        // lanes cover rows R0+4j+{0..3}: lane L -> row R0+4j+(L>>4), cols (L&15)*4..
        float4 m = mbase[j * 64 + L];     // 1 KB contiguous per wave-instruction
        float d = m.x * kf.x + m.y * kf.y + m.z * kf.z + m.w * kf.w;
        float q = m.x * m.x + m.y * m.y + m.z * m.z + m.w * m.w;
        #pragma unroll
        for (int msk = 1; msk < 16; msk <<= 1) {   // reduce within 16-lane row group
            d += __shfl_xor(d, msk, 64);
            q += __shfl_xor(q, msk, 64);
        }
        // row R0+L (L = 4a+b) is computed at iteration a by group b (lanes b*16..)
        float dg = __shfl(d, (L & 3) << 4, 64);
        float qg = __shfl(q, (L & 3) << 4, 64);
        if ((L >> 2) == j) { myDot = dg; myNr = qg; }
    }

    unsigned int n = R0 + (unsigned int)L;       // == blockIdx.x*256 + tid
    float rn = fmaxf(sqrtf(myNr), 1e-8f);
    // |beta * cosine| <= 2 -> no max-subtraction pass needed for softmax
    float e = __expf(c_sh * myDot / rn);
    out[n] = e;

    float4 r = ((const float4*)rw)[n];
    float4 g = *((const float4*)fg);
    float ret = (1.f - r.x * g.x) * (1.f - r.y * g.y) *
                (1.f - r.z * g.z) * (1.f - r.w * g.w);
    float p = pu[n], w2 = wwt[n];
    float u = (p + w2 - p * w2) * ret;

    out[NSL + n]      = ret;
    out[2u * NSL + n] = u;
    out[3u * NSL + n] = 0.f;              // allocation default (tail ~ 0)

    // candidate collection
    if (u < UTH) {
        unsigned int pos = atomicAdd((unsigned int*)ws + 2, 1u);
        if (pos < CAP) {
            ws[WS_CVAL + pos] = u;
            ((unsigned int*)ws)[WS_CIDX + pos] = n;
        }
    }

    // block partial sum of exp (no global atomics)
    float s = e;
    #pragma unroll
    for (int off = 32; off > 0; off >>= 1) s += __shfl_down(s, off);
    if ((tid & 63) == 0) part[tid >> 6] = s;
    __syncthreads();
    if (tid == 0) ws[WS_PART + blockIdx.x] = part[0] + part[1] + part[2] + part[3];
}

// ---- K2: reduce partials; select 64 smallest (u,idx); cumprod scatter alloc
__global__ __launch_bounds__(512) void k_select(float* __restrict__ out,
                                                float* __restrict__ ws)
{
    __shared__ unsigned long long sk[SORTN];
    __shared__ unsigned int hist[NBINS];
    __shared__ unsigned int csum[512];
    __shared__ float pr[8];
    __shared__ unsigned long long wr2[8];
    __shared__ unsigned long long last_sh;
    __shared__ unsigned int c2_sh;
    __shared__ int bcut_sh;
    int tid = threadIdx.x;

    // Phase A: softmax denominator from 4096 per-block partials
    float s = 0.f;
    for (int i = tid; i < NBLK; i += 512) s += ws[WS_PART + i];
    #pragma unroll
    for (int off = 32; off > 0; off >>= 1) s += __shfl_down(s, off);
    if ((tid & 63) == 0) pr[tid >> 6] = s;
    __syncthreads();
    if (tid == 0) {
        float t = 0.f;
        #pragma unroll
        for (int i = 0; i < 8; ++i) t += pr[i];
        ws[1] = 1.f / t;
    }

    int M = (int)((const unsigned int*)ws)[2];
    if (M > CAP) M = CAP;

    // Number of keys that will be bitonic-sorted in LDS, and validity flag.
    int Msort = -1;   // -1 => must use global fallback

    if (M <= SORTN) {
        // small-M path: load everything directly
        for (int i = tid; i < SORTN; i += 512) {
            unsigned long long kk = ~0ull;
            if (i < M)
                kk = ((unsigned long long)__float_as_uint(ws[WS_CVAL + i]) << 32)
                     | (unsigned long long)((const unsigned int*)ws)[WS_CIDX + i];
            sk[i] = kk;
        }
        Msort = M;
        __syncthreads();
    } else {
        // large-M path: histogram select down to <= SORTN survivors.
        // All candidate u < UTH = 0.005 => float bits >> 19 < 0x775 < NBINS,
        // and bits>>19 is monotone in u (u >= 0 always).
        for (int i = tid; i < NBINS; i += 512) hist[i] = 0u;
        __syncthreads();
        for (int i = tid; i < M; i += 512) {
            unsigned int b = __float_as_uint(ws[WS_CVAL + i]) >> 19;
            atomicAdd(&hist[b], 1u);
        }
        __syncthreads();
        // cut bin B: smallest B with count(bins <= B) >= 64
        {
            unsigned int s4 = 0;
            #pragma unroll
            for (int k = 0; k < 4; ++k) s4 += hist[tid * 4 + k];
            csum[tid] = s4;
        }
        __syncthreads();
        if (tid == 0) {
            unsigned int acc = 0;
            int B = NBINS - 1;
            for (int c = 0; c < 512; ++c) {
                if (acc + csum[c] >= 64u) {
                    unsigned int a2 = acc;
                    for (int k = 0; k < 4; ++k) {
                        a2 += hist[c * 4 + k];
                        if (a2 >= 64u) { B = c * 4 + k; break; }
                    }
                    break;
                }
                acc += csum[c];
            }
            bcut_sh = B;
            c2_sh = 0u;
        }
        __syncthreads();
        unsigned int B = (unsigned int)bcut_sh;
        // init sort buffer to +inf keys, then collect bins <= B
        for (int i = tid; i < SORTN; i += 512) sk[i] = ~0ull;
        __syncthreads();
        for (int i = tid; i < M; i += 512) {
            float v = ws[WS_CVAL + i];
            if ((__float_as_uint(v) >> 19) <= B) {
                unsigned int p = atomicAdd(&c2_sh, 1u);
                if (p < SORTN)
                    sk[p] = ((unsigned long long)__float_as_uint(v) << 32)
                            | (unsigned long long)((const unsigned int*)ws)[WS_CIDX + i];
            }
        }
        __syncthreads();
        unsigned int C2 = c2_sh;
        if (C2 <= SORTN) Msort = (int)C2;   // guaranteed superset of global top-64
        // else Msort stays -1 -> global fallback (essentially impossible)
    }

    if (Msort >= 0) {
        // bitonic sort of packed (u_bits<<32 | slot) keys, ascending
        for (int k2 = 2; k2 <= SORTN; k2 <<= 1) {
            for (int j = k2 >> 1; j > 0; j >>= 1) {
                for (int i = tid; i < SORTN; i += 512) {
                    int ixj = i ^ j;
                    if (ixj > i) {
                        bool up = ((i & k2) == 0);
                        unsigned long long a = sk[i], b = sk[ixj];
                        if (up ? (a > b) : (a < b)) { sk[i] = b; sk[ixj] = a; }
                    }
                }
                __syncthreads();
            }
        }
        if (tid == 0) {
            float cum = 1.f, prev = 0.f;
            int K = Msort < 64 ? Msort : 64;
            for (int k = 0; k < K; ++k) {
                unsigned long long b = sk[k];
                float v = __uint_as_float((unsigned int)(b >> 32));
                unsigned int slot = (unsigned int)b;
                float a = (1.f - (k == 0 ? v : prev)) * cum;
                out[3u * NSL + slot] = a;
                cum *= v; prev = v;
            }
        }
    } else {
        // last-resort fallback: 64 rounds of min-above-last over global buffer
        if (tid == 0) last_sh = 0ull;
        __syncthreads();
        float cum = 1.f, prev = 0.f;
        int K = M < 64 ? M : 64;
        for (int k = 0; k < K; ++k) {
            unsigned long long last = last_sh;
            unsigned long long best = ~0ull;
            for (int i = tid; i < M; i += 512) {
                unsigned long long kk =
                    ((unsigned long long)__float_as_uint(ws[WS_CVAL + i]) << 32)
                    | (unsigned long long)((const unsigned int*)ws)[WS_CIDX + i];
                if ((k == 0 || kk > last) && kk < best) best = kk;
            }
            #pragma unroll
            for (int off = 32; off > 0; off >>= 1) {
                unsigned long long o = __shfl_down(best, off);
                if (o < best) best = o;
            }
            if ((tid & 63) == 0) wr2[tid >> 6] = best;
            __syncthreads();
            if (tid == 0) {
                unsigned long long b = ~0ull;
                #pragma unroll
                for (int i = 0; i < 8; ++i) if (wr2[i] < b) b = wr2[i];
                float v = __uint_as_float((unsigned int)(b >> 32));
                unsigned int slot = (unsigned int)b;
                float a = (1.f - (k == 0 ? v : prev)) * cum;
                out[3u * NSL + slot] = a;
                cum *= v; prev = v;
                last_sh = b;
            }
            __syncthreads();
        }
    }
}

// ------------------------------------------- K3: softmax normalization
__global__ __launch_bounds__(256) void k_norm(float* __restrict__ out,
                                              const float* __restrict__ ws) {
    unsigned int i = blockIdx.x * 256u + threadIdx.x;
    float inv = ws[1];
    float4* o = (float4*)out;
    float4 v = o[i];
    v.x *= inv; v.y *= inv; v.z *= inv; v.w *= inv;
    o[i] = v;
}

extern "C" void kernel_launch(void* const* d_in, const int* in_sizes, int n_in,
                              void* d_out, int out_size, void* d_ws, size_t ws_size,
                              hipStream_t stream) {
    const float* key  = (const float*)d_in[0];   // desired_content (64)
    const float* mem  = (const float*)d_in[1];   // memory (N*64)
    const float* beta = (const float*)d_in[2];   // key_strength (1)
    const float* fg   = (const float*)d_in[3];   // free_gate (4)
    const float* rw   = (const float*)d_in[4];   // read_weighting (N*4)
    const float* pu   = (const float*)d_in[5];   // previous_usage (N)
    const float* wwt  = (const float*)d_in[6];   // write_weighting (N)
    float* out = (float*)d_out;
    float* ws  = (float*)d_ws;

    // zero candidate counter (ws poisoned 0xAA before every timed call)
    hipMemsetAsync(ws, 0, 32, stream);
    k_main<<<dim3(NBLK), dim3(256), 0, stream>>>(mem, key, beta, fg, rw, pu, wwt, out, ws);
    k_select<<<dim3(1), dim3(512), 0, stream>>>(out, ws);
    k_norm<<<dim3(NSL / 4 / 256), dim3(256), 0, stream>>>(out, ws);
}

// Round 2
// 439.436 us; speedup vs baseline: 1.0087x; 1.0050x over previous
//
#include <hip/hip_runtime.h>
#include <math.h>

#define NSL   1048576u   // N slots
#define WW    64         // word width
#define NBLK  4096       // k_main grid (NSL/256)
#define CAP   131072     // global candidate buffer capacity
#define SORTN 2048       // LDS bitonic sort capacity
#define NBINS 2048       // histogram bins for large-M select (bits>>19 of u<0.005 => <0x775)
#define UTH   0.005f     // usage candidate threshold; alloc tail beyond candidates
                         // is <= prod(s_i) < UTH^M -> far below 2e-2 harness threshold

// ws float layout:
// [1]                inv softmax sum (k_select -> k_norm)
// [2]                candidate count (uint, atomic; zeroed by memset node)
// [4 .. 4+NBLK)      per-block exp partial sums (no atomics)
// [8192 .. +CAP)     candidate usage values
// [8192+CAP .. +CAP) candidate slot indices (uint)
#define WS_PART 4
#define WS_CVAL 8192
#define WS_CIDX (8192 + CAP)

// ------------------------------------------------- K1: main streaming pass
// 4-lanes-per-row layout: lane L handles 64 contiguous bytes (4 float4) of
// row R0 + 16j + (L>>2) at sub-iteration j (j=0..3). Reduction over a row
// needs only shfl_xor 1,2 (intra-quad) + one broadcast: 24 cross-lane ops
// per 64 rows vs 160 in the previous 16-lane-per-row scheme.
__global__ __launch_bounds__(256) void k_main(
    const float* __restrict__ mem, const float* __restrict__ key,
    const float* __restrict__ beta, const float* __restrict__ fg,
    const float* __restrict__ rw,  const float* __restrict__ pu,
    const float* __restrict__ wwt,
    float* __restrict__ out, float* __restrict__ ws)
{
    __shared__ float kbuf[WW];
    __shared__ float c_sh;
    __shared__ float part[4];
    int tid = threadIdx.x;
    if (tid < WW / 4) ((float4*)kbuf)[tid] = ((const float4*)key)[tid];
    __syncthreads();
    if (tid < 64) {                       // wave 0: key norm + scale factor
        float x = kbuf[tid];
        float s = x * x;
        #pragma unroll
        for (int off = 32; off > 0; off >>= 1) s += __shfl_down(s, off);
        if (tid == 0) c_sh = beta[0] / fmaxf(sqrtf(s), 1e-8f);
    }
    __syncthreads();

    int w = tid >> 6;                     // wave id 0..3
    int L = tid & 63;                     // lane id
    unsigned int R0 = blockIdx.x * 256u + (unsigned int)(w * 64);  // wave row base
    unsigned int n = R0 + (unsigned int)L;       // this lane's output row

    // hoist epilogue inputs so their latency hides under the dot loop
    float4 r  = ((const float4*)rw)[n];
    float4 g  = *((const float4*)fg);
    float  p  = pu[n], w2 = wwt[n];

    int c = L & 3;                        // 64B chunk within row
    float4 kf0 = ((const float4*)kbuf)[c * 4 + 0];
    float4 kf1 = ((const float4*)kbuf)[c * 4 + 1];
    float4 kf2 = ((const float4*)kbuf)[c * 4 + 2];
    float4 kf3 = ((const float4*)kbuf)[c * 4 + 3];

    // lane's load base: row (R0 + L>>2), float4s c*4 .. c*4+3
    const float4* mbase = (const float4*)mem
                        + (size_t)R0 * (WW / 4)
                        + (size_t)(L >> 2) * (WW / 4) + (size_t)c * 4;

    float myDot = 0.f, myNr = 0.f;        // final values for row R0 + L
    #pragma unroll
    for (int j = 0; j < 4; ++j) {
        const float4* pj = mbase + j * 16 * (WW / 4);   // +16 rows per sub-iter
        float4 m0 = pj[0], m1 = pj[1], m2 = pj[2], m3 = pj[3];
        float d = m0.x * kf0.x + m0.y * kf0.y + m0.z * kf0.z + m0.w * kf0.w
                + m1.x * kf1.x + m1.y * kf1.y + m1.z * kf1.z + m1.w * kf1.w
                + m2.x * kf2.x + m2.y * kf2.y + m2.z * kf2.z + m2.w * kf2.w
                + m3.x * kf3.x + m3.y * kf3.y + m3.z * kf3.z + m3.w * kf3.w;
        float q = m0.x * m0.x + m0.y * m0.y + m0.z * m0.z + m0.w * m0.w
                + m1.x * m1.x + m1.y * m1.y + m1.z * m1.z + m1.w * m1.w
                + m2.x * m2.x + m2.y * m2.y + m2.z * m2.z + m2.w * m2.w
                + m3.x * m3.x + m3.y * m3.y + m3.z * m3.z + m3.w * m3.w;
        // reduce across the 4 lanes of this row's quad
        d += __shfl_xor(d, 1, 64); d += __shfl_xor(d, 2, 64);
        q += __shfl_xor(q, 1, 64); q += __shfl_xor(q, 2, 64);
        // row R0+L lives at sub-iter j = L>>4 in quad (L&15): grab from lane 4*(L&15)
        float dg = __shfl(d, (L & 15) << 2, 64);
        float qg = __shfl(q, (L & 15) << 2, 64);
        if ((L >> 4) == j) { myDot = dg; myNr = qg; }
    }

    float rn = fmaxf(sqrtf(myNr), 1e-8f);
    // |beta * cosine| <= 2 -> no max-subtraction pass needed for softmax
    float e = __expf(c_sh * myDot / rn);
    out[n] = e;

    float ret = (1.f - r.x * g.x) * (1.f - r.y * g.y) *
                (1.f - r.z * g.z) * (1.f - r.w * g.w);
    float u = (p + w2 - p * w2) * ret;

    out[NSL + n]      = ret;
    out[2u * NSL + n] = u;
    out[3u * NSL + n] = 0.f;              // allocation default (tail ~ 0)

    // candidate collection
    if (u < UTH) {
        unsigned int pos = atomicAdd((unsigned int*)ws + 2, 1u);
        if (pos < CAP) {
            ws[WS_CVAL + pos] = u;
            ((unsigned int*)ws)[WS_CIDX + pos] = n;
        }
    }

    // block partial sum of exp (no global atomics)
    float s = e;
    #pragma unroll
    for (int off = 32; off > 0; off >>= 1) s += __shfl_down(s, off);
    if ((tid & 63) == 0) part[tid >> 6] = s;
    __syncthreads();
    if (tid == 0) ws[WS_PART + blockIdx.x] = part[0] + part[1] + part[2] + part[3];
}

// ---- K2: reduce partials; select 64 smallest (u,idx); cumprod scatter alloc
__global__ __launch_bounds__(512) void k_select(float* __restrict__ out,
                                                float* __restrict__ ws)
{
    __shared__ unsigned long long sk[SORTN];
    __shared__ unsigned int hist[NBINS];
    __shared__ unsigned int csum[512];
    __shared__ float pr[8];
    __shared__ unsigned long long wr2[8];
    __shared__ unsigned long long last_sh;
    __shared__ unsigned int c2_sh;
    __shared__ int bcut_sh;
    int tid = threadIdx.x;

    // Phase A: softmax denominator from 4096 per-block partials
    float s = 0.f;
    for (int i = tid; i < NBLK; i += 512) s += ws[WS_PART + i];
    #pragma unroll
    for (int off = 32; off > 0; off >>= 1) s += __shfl_down(s, off);
    if ((tid & 63) == 0) pr[tid >> 6] = s;
    __syncthreads();
    if (tid == 0) {
        float t = 0.f;
        #pragma unroll
        for (int i = 0; i < 8; ++i) t += pr[i];
        ws[1] = 1.f / t;
    }

    int M = (int)((const unsigned int*)ws)[2];
    if (M > CAP) M = CAP;

    // Number of keys that will be bitonic-sorted in LDS, and validity flag.
    int Msort = -1;   // -1 => must use global fallback

    if (M <= SORTN) {
        // small-M path (the expected path, M ~ 100..1500): load directly
        for (int i = tid; i < SORTN; i += 512) {
            unsigned long long kk = ~0ull;
            if (i < M)
                kk = ((unsigned long long)__float_as_uint(ws[WS_CVAL + i]) << 32)
                     | (unsigned long long)((const unsigned int*)ws)[WS_CIDX + i];
            sk[i] = kk;
        }
        Msort = M;
        __syncthreads();
    } else {
        // large-M path: histogram select down to <= SORTN survivors.
        // All candidate u < UTH = 0.005 => float bits >> 19 < 0x775 < NBINS,
        // and bits>>19 is monotone in u (u >= 0 always).
        for (int i = tid; i < NBINS; i += 512) hist[i] = 0u;
        __syncthreads();
        for (int i = tid; i < M; i += 512) {
            unsigned int b = __float_as_uint(ws[WS_CVAL + i]) >> 19;
            atomicAdd(&hist[b], 1u);
        }
        __syncthreads();
        // cut bin B: smallest B with count(bins <= B) >= 64
        {
            unsigned int s4 = 0;
            #pragma unroll
            for (int k = 0; k < 4; ++k) s4 += hist[tid * 4 + k];
            csum[tid] = s4;
        }
        __syncthreads();
        if (tid == 0) {
            unsigned int acc = 0;
            int B = NBINS - 1;
            for (int c = 0; c < 512; ++c) {
                if (acc + csum[c] >= 64u) {
                    unsigned int a2 = acc;
                    for (int k = 0; k < 4; ++k) {
                        a2 += hist[c * 4 + k];
                        if (a2 >= 64u) { B = c * 4 + k; break; }
                    }
                    break;
                }
                acc += csum[c];
            }
            bcut_sh = B;
            c2_sh = 0u;
        }
        __syncthreads();
        unsigned int B = (unsigned int)bcut_sh;
        // init sort buffer to +inf keys, then collect bins <= B
        for (int i = tid; i < SORTN; i += 512) sk[i] = ~0ull;
        __syncthreads();
        for (int i = tid; i < M; i += 512) {
            float v = ws[WS_CVAL + i];
            if ((__float_as_uint(v) >> 19) <= B) {
                unsigned int p = atomicAdd(&c2_sh, 1u);
                if (p < SORTN)
                    sk[p] = ((unsigned long long)__float_as_uint(v) << 32)
                            | (unsigned long long)((const unsigned int*)ws)[WS_CIDX + i];
            }
        }
        __syncthreads();
        unsigned int C2 = c2_sh;
        if (C2 <= SORTN) Msort = (int)C2;   // guaranteed superset of global top-64
        // else Msort stays -1 -> global fallback (essentially impossible)
    }

    if (Msort >= 0) {
        // bitonic sort of packed (u_bits<<32 | slot) keys, ascending.
        // dynamic size: next pow2 >= max(Msort, 64); slots beyond Msort are ~0ull
        int SN = 64;
        while (SN < Msort) SN <<= 1;      // Msort <= SORTN -> SN <= SORTN
        for (int k2 = 2; k2 <= SN; k2 <<= 1) {
            for (int j = k2 >> 1; j > 0; j >>= 1) {
                for (int i = tid; i < SN; i += 512) {
                    int ixj = i ^ j;
                    if (ixj > i) {
                        bool up = ((i & k2) == 0);
                        unsigned long long a = sk[i], b = sk[ixj];
                        if (up ? (a > b) : (a < b)) { sk[i] = b; sk[ixj] = a; }
                    }
                }
                __syncthreads();
            }
        }
        if (tid == 0) {
            float cum = 1.f, prev = 0.f;
            int K = Msort < 64 ? Msort : 64;
            for (int k = 0; k < K; ++k) {
                unsigned long long b = sk[k];
                float v = __uint_as_float((unsigned int)(b >> 32));
                unsigned int slot = (unsigned int)b;
                float a = (1.f - (k == 0 ? v : prev)) * cum;
                out[3u * NSL + slot] = a;
                cum *= v; prev = v;
            }
        }
    } else {
        // last-resort fallback: 64 rounds of min-above-last over global buffer
        if (tid == 0) last_sh = 0ull;
        __syncthreads();
        float cum = 1.f, prev = 0.f;
        int K = M < 64 ? M : 64;
        for (int k = 0; k < K; ++k) {
            unsigned long long last = last_sh;
            unsigned long long best = ~0ull;
            for (int i = tid; i < M; i += 512) {
                unsigned long long kk =
                    ((unsigned long long)__float_as_uint(ws[WS_CVAL + i]) << 32)
                    | (unsigned long long)((const unsigned int*)ws)[WS_CIDX + i];
                if ((k == 0 || kk > last) && kk < best) best = kk;
            }
            #pragma unroll
            for (int off = 32; off > 0; off >>= 1) {
                unsigned long long o = __shfl_down(best, off);
                if (o < best) best = o;
            }
            if ((tid & 63) == 0) wr2[tid >> 6] = best;
            __syncthreads();
            if (tid == 0) {
                unsigned long long b = ~0ull;
                #pragma unroll
                for (int i = 0; i < 8; ++i) if (wr2[i] < b) b = wr2[i];
                float v = __uint_as_float((unsigned int)(b >> 32));
                unsigned int slot = (unsigned int)b;
                float a = (1.f - (k == 0 ? v : prev)) * cum;
                out[3u * NSL + slot] = a;
                cum *= v; prev = v;
                last_sh = b;
            }
            __syncthreads();
        }
    }
}

// ------------------------------------------- K3: softmax normalization
__global__ __launch_bounds__(256) void k_norm(float* __restrict__ out,
                                              const float* __restrict__ ws) {
    unsigned int i = blockIdx.x * 256u + threadIdx.x;
    float inv = ws[1];
    float4* o = (float4*)out;
    float4 v = o[i];
    v.x *= inv; v.y *= inv; v.z *= inv; v.w *= inv;
    o[i] = v;
}

extern "C" void kernel_launch(void* const* d_in, const int* in_sizes, int n_in,
                              void* d_out, int out_size, void* d_ws, size_t ws_size,
                              hipStream_t stream) {
    const float* key  = (const float*)d_in[0];   // desired_content (64)
    const float* mem  = (const float*)d_in[1];   // memory (N*64)
    const float* beta = (const float*)d_in[2];   // key_strength (1)
    const float* fg   = (const float*)d_in[3];   // free_gate (4)
    const float* rw   = (const float*)d_in[4];   // read_weighting (N*4)
    const float* pu   = (const float*)d_in[5];   // previous_usage (N)
    const float* wwt  = (const float*)d_in[6];   // write_weighting (N)
    float* out = (float*)d_out;
    float* ws  = (float*)d_ws;

    // zero candidate counter (ws poisoned 0xAA before every timed call)
    hipMemsetAsync(ws, 0, 32, stream);
    k_main<<<dim3(NBLK), dim3(256), 0, stream>>>(mem, key, beta, fg, rw, pu, wwt, out, ws);
    k_select<<<dim3(1), dim3(512), 0, stream>>>(out, ws);
    k_norm<<<dim3(NSL / 4 / 256), dim3(256), 0, stream>>>(out, ws);
}